// Round 3
// baseline (654.554 us; speedup 1.0000x reference)
//
#include <hip/hip_runtime.h>
#include <math.h>

// NoisyTopKRouter: B=4, T=4096, C=2048, E=64, K=8; rows = 16384.
// Split-bf16 MFMA GEMM (x = hi+lo bf16; 3 MFMAs per frag pair -> fp32-class
// accuracy at bf16 matrix rate) + fused epilogue with f64 near-tie repair.

#define CDIM 2048
#define EDIM 64
#define NOUT 128   // 64 route + 64 noise
#define TOPK 8
#define BM   64    // rows per block
#define BK   32    // k-chunk
#define NIT  (CDIM / BK)
#define TAU  1e-3f
#define LGS  132   // logits LDS row stride

typedef __attribute__((ext_vector_type(8))) short bf16x8;  // 8 bf16 = 4 VGPRs
typedef __attribute__((ext_vector_type(4))) float f32x4;

#define AS3(p) ((__attribute__((address_space(3))) void*)(p))
#define AS1(p) ((const __attribute__((address_space(1))) void*)(p))

__global__ __launch_bounds__(256, 1)
void router_mfma(const float* __restrict__ x,
                 const float* __restrict__ w_route,
                 const float* __restrict__ w_noise,
                 const float* __restrict__ noise,
                 float* __restrict__ out_probs,
                 float* __restrict__ out_idx)
{
    // staging: xs[2][BM][BK] f32 (16 KB) + ws[2][NOUT][BK] f32 (32 KB) = 48 KB
    // logits (64 x LGS f32 = 33 KB) alias the staging region after the k-loop.
    __shared__ __align__(16) float smem[2 * BM * BK + 2 * NOUT * BK];
    float* xs = smem;
    float* ws = smem + 2 * BM * BK;

    const int tid  = (int)threadIdx.x;
    const int lane = tid & 63;
    const int wid  = tid >> 6;       // wave 0..3
    const int wr   = wid >> 1;       // row half (32 rows)
    const int wc   = wid & 1;        // col half (64 cols)
    const int row0 = (int)blockIdx.x * BM;
    const int l15  = lane & 15;
    const int q8   = (lane >> 4) * 8;
    const int lr   = lane >> 3;      // staging: row within 8-row chunk
    const int lk   = (lane & 7) * 4; // staging: k offset (f32)

    f32x4 acc[2][4];
    #pragma unroll
    for (int mr = 0; mr < 2; ++mr)
        #pragma unroll
        for (int nc = 0; nc < 4; ++nc)
            acc[mr][nc] = (f32x4){0.f, 0.f, 0.f, 0.f};

    // async global -> LDS staging of k-chunk starting at k0 into buffer b.
    // LDS dest is wave-uniform base; HW writes base + lane*16 (= [row][k] order).
    auto stage = [&](int b, int k0) {
        float* xbuf = xs + b * (BM * BK);
        float* wbuf = ws + b * (NOUT * BK);
        #pragma unroll
        for (int c = 0; c < 2; ++c) {
            const int r = wid * 16 + c * 8;
            const float* g = x + (size_t)(row0 + r + lr) * CDIM + (k0 + lk);
            __builtin_amdgcn_global_load_lds(AS1(g), AS3(xbuf + r * BK), 16, 0, 0);
        }
        #pragma unroll
        for (int c = 0; c < 4; ++c) {
            const int e = wid * 32 + c * 8;   // 0..127, uniform side of 64 per issue
            const float* srcb = (e < EDIM) ? (w_route + (size_t)(e + lr) * CDIM)
                                           : (w_noise + (size_t)(e - EDIM + lr) * CDIM);
            __builtin_amdgcn_global_load_lds(AS1(srcb + k0 + lk), AS3(wbuf + e * BK), 16, 0, 0);
        }
    };

    stage(0, 0);
    for (int it = 0; it < NIT; ++it) {
        const int cur = it & 1;
        __syncthreads();   // drains stage(it) (vmcnt) + prior-iter LDS reads
        if (it + 1 < NIT) stage(cur ^ 1, (it + 1) * BK);  // prefetch overlaps MFMA below

        const float* xb = xs + cur * (BM * BK);
        const float* wb = ws + cur * (NOUT * BK);

        bf16x8 ah[2], al[2], bh[4], bl[4];
        #pragma unroll
        for (int mr = 0; mr < 2; ++mr) {
            const float* p = xb + (wr * 32 + mr * 16 + l15) * BK + q8;
            const float4 v0 = *(const float4*)p;
            const float4 v1 = *(const float4*)(p + 4);
            const float vv[8] = {v0.x, v0.y, v0.z, v0.w, v1.x, v1.y, v1.z, v1.w};
            #pragma unroll
            for (int j = 0; j < 8; ++j) {
                const __bf16 h = (__bf16)vv[j];
                const __bf16 l = (__bf16)(vv[j] - (float)h);
                ah[mr][j] = __builtin_bit_cast(short, h);
                al[mr][j] = __builtin_bit_cast(short, l);
            }
        }
        #pragma unroll
        for (int nc = 0; nc < 4; ++nc) {
            const float* p = wb + (wc * 64 + nc * 16 + l15) * BK + q8;
            const float4 v0 = *(const float4*)p;
            const float4 v1 = *(const float4*)(p + 4);
            const float vv[8] = {v0.x, v0.y, v0.z, v0.w, v1.x, v1.y, v1.z, v1.w};
            #pragma unroll
            for (int j = 0; j < 8; ++j) {
                const __bf16 h = (__bf16)vv[j];
                const __bf16 l = (__bf16)(vv[j] - (float)h);
                bh[nc][j] = __builtin_bit_cast(short, h);
                bl[nc][j] = __builtin_bit_cast(short, l);
            }
        }
        #pragma unroll
        for (int mr = 0; mr < 2; ++mr)
            #pragma unroll
            for (int nc = 0; nc < 4; ++nc) {
                acc[mr][nc] = __builtin_amdgcn_mfma_f32_16x16x32_bf16(ah[mr], bh[nc], acc[mr][nc], 0, 0, 0);
                acc[mr][nc] = __builtin_amdgcn_mfma_f32_16x16x32_bf16(al[mr], bh[nc], acc[mr][nc], 0, 0, 0);
                acc[mr][nc] = __builtin_amdgcn_mfma_f32_16x16x32_bf16(ah[mr], bl[nc], acc[mr][nc], 0, 0, 0);
            }
    }

    // ---- logits to LDS (C/D layout: row = quad*4+reg, col = lane&15)
    __syncthreads();
    float* lg = smem;   // 64 x LGS, aliases staging
    const int q4 = (lane >> 4) * 4;
    #pragma unroll
    for (int mr = 0; mr < 2; ++mr)
        #pragma unroll
        for (int nc = 0; nc < 4; ++nc)
            #pragma unroll
            for (int g = 0; g < 4; ++g) {
                const int rl = wr * 32 + mr * 16 + q4 + g;
                const int cl = wc * 64 + nc * 16 + l15;
                lg[rl * LGS + cl] = acc[mr][nc][g];
            }
    __syncthreads();

    // ---- epilogue: each wave handles 16 rows; lane == expert index
    for (int rr = 0; rr < 16; ++rr) {
        const int r    = wid * 16 + rr;
        const int grow = row0 + r;
        const float route = lg[r * LGS + lane];
        const float nz    = lg[r * LGS + EDIM + lane];
        const float nv    = noise[(size_t)grow * EDIM + lane];
        const float sp = fmaxf(nz, 0.f) + log1pf(expf(-fabsf(nz)));
        const float nl = route + nv * sp;

        // top-8 + 9th value, tracking min adjacent gap for near-tie repair
        float work = nl;
        int   rank = -1;
        float m = 0.f, prev = 0.f, min_gap = INFINITY;
        #pragma unroll
        for (int t = 0; t <= TOPK; ++t) {
            float bv = work;
            int   bi = lane;
            #pragma unroll
            for (int off = 32; off >= 1; off >>= 1) {
                float ov = __shfl_xor(bv, off, 64);
                int   oi = __shfl_xor(bi, off, 64);
                if (ov > bv || (ov == bv && oi < bi)) { bv = ov; bi = oi; }
            }
            if (t == 0) m = bv; else min_gap = fminf(min_gap, prev - bv);
            prev = bv;
            if (lane == bi) {
                if (t < TOPK) rank = t;
                work = -INFINITY;
            }
        }

        if (min_gap >= TAU) {
            if (rank >= 0) out_idx[(size_t)grow * TOPK + rank] = (float)lane;
            float ev = (rank >= 0) ? expf(nl - m) : 0.f;
            float s  = ev;
            #pragma unroll
            for (int off = 32; off >= 1; off >>= 1) s += __shfl_xor(s, off, 64);
            out_probs[(size_t)grow * EDIM + lane] = ev / s;
        } else {
            // near-tie: exact f64 recompute of this row's 128 logits
            const float* xr = x + (size_t)grow * CDIM;
            const float* wrp = w_route + (size_t)lane * CDIM;
            const float* wnp = w_noise + (size_t)lane * CDIM;
            double ar = 0.0, an = 0.0;
            for (int k = 0; k < CDIM; k += 4) {
                const float4 xv = *(const float4*)(xr + k);
                const float4 rv = *(const float4*)(wrp + k);
                const float4 nq = *(const float4*)(wnp + k);
                ar = fma((double)xv.x, (double)rv.x, ar);
                ar = fma((double)xv.y, (double)rv.y, ar);
                ar = fma((double)xv.z, (double)rv.z, ar);
                ar = fma((double)xv.w, (double)rv.w, ar);
                an = fma((double)xv.x, (double)nq.x, an);
                an = fma((double)xv.y, (double)nq.y, an);
                an = fma((double)xv.z, (double)nq.z, an);
                an = fma((double)xv.w, (double)nq.w, an);
            }
            const double spd  = fmax(an, 0.0) + log1p(exp(-fabs(an)));
            const double nl64 = ar + (double)nv * spd;

            double workd = nl64;
            int    rank64 = -1;
            double m64 = 0.0;
            #pragma unroll
            for (int t = 0; t < TOPK; ++t) {
                double bv = workd;
                int    bi = lane;
                #pragma unroll
                for (int off = 32; off >= 1; off >>= 1) {
                    double ov = __shfl_xor(bv, off, 64);
                    int    oi = __shfl_xor(bi, off, 64);
                    if (ov > bv || (ov == bv && oi < bi)) { bv = ov; bi = oi; }
                }
                if (t == 0) m64 = bv;
                if (lane == bi) {
                    rank64 = t;
                    workd = -INFINITY;
                    out_idx[(size_t)grow * TOPK + t] = (float)lane;
                }
            }
            float ev = (rank64 >= 0) ? expf((float)(nl64 - m64)) : 0.f;
            float s  = ev;
            #pragma unroll
            for (int off = 32; off >= 1; off >>= 1) s += __shfl_xor(s, off, 64);
            out_probs[(size_t)grow * EDIM + lane] = ev / s;
        }
    }
}

extern "C" void kernel_launch(void* const* d_in, const int* in_sizes, int n_in,
                              void* d_out, int out_size, void* d_ws, size_t ws_size,
                              hipStream_t stream)
{
    const float* x       = (const float*)d_in[0];
    const float* w_route = (const float*)d_in[1];
    const float* w_noise = (const float*)d_in[2];
    const float* noise   = (const float*)d_in[3];

    const int n_rows = in_sizes[0] / CDIM;                 // 16384
    float* out_probs = (float*)d_out;                      // (B,T,E) fp32
    float* out_idx   = out_probs + (size_t)n_rows * EDIM;  // (B,T,K) as fp32

    dim3 grid(n_rows / BM);   // 256 blocks
    dim3 block(256);
    hipLaunchKernelGGL(router_mfma, grid, block, 0, stream,
                       x, w_route, w_noise, noise, out_probs, out_idx);
}

// Round 4
// 361.900 us; speedup vs baseline: 1.8087x; 1.8087x over previous
//
#include <hip/hip_runtime.h>
#include <math.h>

// NoisyTopKRouter: B=4, T=4096, C=2048, E=64, K=8; rows = 16384.
// Split-bf16 MFMA GEMM. w pre-split to hi/lo bf16 in d_ws (B frags direct from
// global, L2-resident). x staged via LDS, split once per element, padded pitch
// (conflict-free). Epilogue: top-8 + sparse softmax; near-tie boundaries
// repaired with selective exact-f64 dots (wave-cooperative, coalesced).

#define CDIM 2048
#define EDIM 64
#define NOUT 128
#define TOPK 8
#define BM   32            // rows per block
#define BK   64            // k-chunk
#define NIT  (CDIM / BK)   // 32
#define TAU  1e-3f
#define XP   152           // xsh row pitch (shorts): 76 dwords = 12 mod 32 -> conflict-free
#define LGS  132           // logits LDS pitch

typedef __attribute__((ext_vector_type(8))) short bf16x8;
typedef __attribute__((ext_vector_type(4))) float f32x4;

__device__ __forceinline__ void split8(const float4 a, const float4 b,
                                       bf16x8& h8, bf16x8& l8) {
    const float vv[8] = {a.x, a.y, a.z, a.w, b.x, b.y, b.z, b.w};
    #pragma unroll
    for (int j = 0; j < 8; ++j) {
        const __bf16 h  = (__bf16)vv[j];       // RN
        const float  hf = (float)h;
        const __bf16 l  = (__bf16)(vv[j] - hf); // exact residual, RN to bf16
        h8[j] = __builtin_bit_cast(short, h);
        l8[j] = __builtin_bit_cast(short, l);
    }
}

// ---- kernel 1: split w_route|w_noise (128 x 2048 f32) into hi/lo bf16 arrays
__global__ __launch_bounds__(256) void convert_w(const float* __restrict__ wr,
                                                 const float* __restrict__ wn,
                                                 short* __restrict__ whi,
                                                 short* __restrict__ wlo) {
    const int p   = ((int)blockIdx.x * 256 + (int)threadIdx.x) * 8;  // 0..262136
    const int row = p >> 11;
    const float* src = (row < EDIM) ? (wr + p) : (wn + p - EDIM * CDIM);
    const float4 a = *(const float4*)src;
    const float4 b = *(const float4*)(src + 4);
    bf16x8 h8, l8;
    split8(a, b, h8, l8);
    *(bf16x8*)(whi + p) = h8;
    *(bf16x8*)(wlo + p) = l8;
}

// ---- kernel 2: fused router
__global__ __launch_bounds__(256, 2)
void router_mfma(const float* __restrict__ x,
                 const float* __restrict__ w_route,
                 const float* __restrict__ w_noise,
                 const float* __restrict__ noise,
                 const short* __restrict__ whi,
                 const short* __restrict__ wlo,
                 float* __restrict__ out_probs,
                 float* __restrict__ out_idx)
{
    __shared__ __align__(16) short xsh[2][BM][XP];   // hi[64] | lo[64] | pad -> 19.0 KB
    __shared__ float lg[BM][LGS];                    // 16.9 KB

    const int tid  = (int)threadIdx.x;
    const int lane = tid & 63;
    const int wid  = tid >> 6;
    const int wr   = wid >> 1;        // row half (16 rows)
    const int wc   = wid & 1;         // col half (64 cols)
    const int row0 = (int)blockIdx.x * BM;
    const int l15  = lane & 15;
    const int q8   = (lane >> 4) * 8;
    const int q4   = (lane >> 4) * 4;

    // staging role: wave stages rows wid*8..+7; lane covers 8 consecutive k
    const int srow = (wid << 3) + (lane >> 3);
    const int skk  = (lane & 7) * 8;
    const float* xsrc = x + (size_t)(row0 + srow) * CDIM + skk;

    f32x4 acc[4];
    #pragma unroll
    for (int nc = 0; nc < 4; ++nc) acc[nc] = (f32x4){0.f, 0.f, 0.f, 0.f};

    // prologue: stage k-chunk 0
    {
        const float4 a = *(const float4*)xsrc;
        const float4 b = *(const float4*)(xsrc + 4);
        bf16x8 h8, l8; split8(a, b, h8, l8);
        short* base = &xsh[0][srow][0];
        *(bf16x8*)(base + skk)      = h8;
        *(bf16x8*)(base + BK + skk) = l8;
    }

    for (int it = 0; it < NIT; ++it) {
        __syncthreads();
        const int  cur = it & 1;
        const bool pf  = (it + 1 < NIT);
        float4 pa, pb;
        if (pf) {   // issue next x loads early; convert after MFMAs
            const float* g = xsrc + (it + 1) * BK;
            pa = *(const float4*)g;
            pb = *(const float4*)(g + 4);
        }
        // A fragments from LDS (hi/lo pre-split, conflict-free pitch)
        const short* arow = &xsh[cur][wr * 16 + l15][0];
        bf16x8 ah[2], al[2];
        #pragma unroll
        for (int h = 0; h < 2; ++h) {
            ah[h] = *(const bf16x8*)(arow + h * 32 + q8);
            al[h] = *(const bf16x8*)(arow + BK + h * 32 + q8);
        }
        // B fragments direct from global (L2-resident, 1 MB total)
        const int k0 = it * BK;
        bf16x8 bh[2][4], bl[2][4];
        #pragma unroll
        for (int nc = 0; nc < 4; ++nc) {
            const size_t off = (size_t)(wc * 64 + nc * 16 + l15) * CDIM + k0 + q8;
            #pragma unroll
            for (int h = 0; h < 2; ++h) {
                bh[h][nc] = *(const bf16x8*)(whi + off + h * 32);
                bl[h][nc] = *(const bf16x8*)(wlo + off + h * 32);
            }
        }
        #pragma unroll
        for (int h = 0; h < 2; ++h)
            #pragma unroll
            for (int nc = 0; nc < 4; ++nc) {
                acc[nc] = __builtin_amdgcn_mfma_f32_16x16x32_bf16(ah[h], bh[h][nc], acc[nc], 0, 0, 0);
                acc[nc] = __builtin_amdgcn_mfma_f32_16x16x32_bf16(al[h], bh[h][nc], acc[nc], 0, 0, 0);
                acc[nc] = __builtin_amdgcn_mfma_f32_16x16x32_bf16(ah[h], bl[h][nc], acc[nc], 0, 0, 0);
            }
        if (pf) {   // x has had the whole MFMA phase to land
            bf16x8 h8, l8; split8(pa, pb, h8, l8);
            short* base = &xsh[cur ^ 1][srow][0];
            *(bf16x8*)(base + skk)      = h8;
            *(bf16x8*)(base + BK + skk) = l8;
        }
    }

    // C/D layout: row = quad*4+reg, col = lane&15
    #pragma unroll
    for (int nc = 0; nc < 4; ++nc)
        #pragma unroll
        for (int g = 0; g < 4; ++g)
            lg[wr * 16 + q4 + g][wc * 64 + nc * 16 + l15] = acc[nc][g];
    __syncthreads();

    // ---- epilogue: 4 waves x 8 rows; lane == expert index
    for (int rr = 0; rr < 8; ++rr) {
        const int r    = (wid << 3) + rr;
        const int grow = row0 + r;
        const float route = lg[r][lane];
        const float nz    = lg[r][EDIM + lane];
        const float nv    = noise[(size_t)grow * EDIM + lane];
        const float sp = fmaxf(nz, 0.f) + log1pf(expf(-fabsf(nz)));
        const float nl = route + nv * sp;

        // top-8 + 9th, recording ambiguous boundaries (gap < TAU)
        float work = nl;
        int   rank = -1;
        float m = 0.f, prev = 0.f;
        bool amb = false, flagme = false;
        #pragma unroll
        for (int t = 0; t <= TOPK; ++t) {
            float bv = work;
            int   bi = lane;
            #pragma unroll
            for (int off = 32; off >= 1; off >>= 1) {
                const float ov = __shfl_xor(bv, off, 64);
                const int   oi = __shfl_xor(bi, off, 64);
                if (ov > bv || (ov == bv && oi < bi)) { bv = ov; bi = oi; }
            }
            if (t == 0) m = bv;
            else if (prev - bv < TAU) {
                amb = true;
                const float vb = 0.5f * (prev + bv);
                flagme = flagme || (fabsf(nl - vb) <= TAU);
            }
            prev = bv;
            if (lane == bi) { if (t < TOPK) rank = t; work = -INFINITY; }
        }

        if (!amb) {
            if (rank >= 0) out_idx[(size_t)grow * TOPK + rank] = (float)lane;
            float ev = (rank >= 0) ? expf(nl - m) : 0.f;
            float s  = ev;
            #pragma unroll
            for (int off = 32; off >= 1; off >>= 1) s += __shfl_xor(s, off, 64);
            out_probs[(size_t)grow * EDIM + lane] = ev / s;
        } else {
            // selective f64 repair: exact dots only for flagged experts
            unsigned long long mask = __ballot(flagme);
            double nld = (double)nl;
            const float* xr = x + (size_t)grow * CDIM;
            while (mask) {
                const int e = (int)__ffsll((unsigned long long)mask) - 1;
                mask &= (mask - 1);
                double ar = 0.0, an = 0.0;
                const float* wrp = w_route + (size_t)e * CDIM;
                const float* wnp = w_noise + (size_t)e * CDIM;
                #pragma unroll
                for (int j = 0; j < 8; ++j) {
                    const int k = (j * 64 + lane) * 4;   // coalesced
                    const float4 xv = *(const float4*)(xr + k);
                    const float4 rv = *(const float4*)(wrp + k);
                    const float4 nq = *(const float4*)(wnp + k);
                    ar = fma((double)xv.x, (double)rv.x, ar);
                    ar = fma((double)xv.y, (double)rv.y, ar);
                    ar = fma((double)xv.z, (double)rv.z, ar);
                    ar = fma((double)xv.w, (double)rv.w, ar);
                    an = fma((double)xv.x, (double)nq.x, an);
                    an = fma((double)xv.y, (double)nq.y, an);
                    an = fma((double)xv.z, (double)nq.z, an);
                    an = fma((double)xv.w, (double)nq.w, an);
                }
                #pragma unroll
                for (int off = 32; off >= 1; off >>= 1) {
                    ar += __shfl_xor(ar, off, 64);
                    an += __shfl_xor(an, off, 64);
                }
                const double spd = fmax(an, 0.0) + log1p(exp(-fabs(an)));
                const double nve = (double)__shfl(nv, e, 64);
                const double v   = ar + nve * spd;
                if (lane == e) nld = v;
            }
            // f64 top-8 scan over mixed (exact for flagged, fp32-upcast otherwise)
            double workd = nld;
            int    rank2 = -1;
            double m2 = 0.0;
            #pragma unroll
            for (int t = 0; t < TOPK; ++t) {
                double bv = workd;
                int    bi = lane;
                #pragma unroll
                for (int off = 32; off >= 1; off >>= 1) {
                    const double ov = __shfl_xor(bv, off, 64);
                    const int    oi = __shfl_xor(bi, off, 64);
                    if (ov > bv || (ov == bv && oi < bi)) { bv = ov; bi = oi; }
                }
                if (t == 0) m2 = bv;
                if (lane == bi) {
                    rank2 = t;
                    workd = -INFINITY;
                    out_idx[(size_t)grow * TOPK + t] = (float)lane;
                }
            }
            float ev = (rank2 >= 0) ? expf((float)(nld - m2)) : 0.f;
            float s  = ev;
            #pragma unroll
            for (int off = 32; off >= 1; off >>= 1) s += __shfl_xor(s, off, 64);
            out_probs[(size_t)grow * EDIM + lane] = ev / s;
        }
    }
}

extern "C" void kernel_launch(void* const* d_in, const int* in_sizes, int n_in,
                              void* d_out, int out_size, void* d_ws, size_t ws_size,
                              hipStream_t stream)
{
    const float* x       = (const float*)d_in[0];
    const float* w_route = (const float*)d_in[1];
    const float* w_noise = (const float*)d_in[2];
    const float* noise   = (const float*)d_in[3];

    const int n_rows = in_sizes[0] / CDIM;                 // 16384
    float* out_probs = (float*)d_out;                      // (B,T,E) fp32
    float* out_idx   = out_probs + (size_t)n_rows * EDIM;  // (B,T,K) as fp32

    short* whi = (short*)d_ws;                             // 128*2048 bf16 hi
    short* wlo = whi + NOUT * CDIM;                        // 128*2048 bf16 lo

    hipLaunchKernelGGL(convert_w, dim3(NOUT * CDIM / (256 * 8)), dim3(256), 0, stream,
                       w_route, w_noise, whi, wlo);
    hipLaunchKernelGGL(router_mfma, dim3(n_rows / BM), dim3(256), 0, stream,
                       x, w_route, w_noise, noise, whi, wlo, out_probs, out_idx);
}

// Round 5
// 346.308 us; speedup vs baseline: 1.8901x; 1.0450x over previous
//
#include <hip/hip_runtime.h>
#include <math.h>

// NoisyTopKRouter: B=4, T=4096, C=2048, E=64, K=8; rows = 16384.
// 3 kernels: (1) convert_w: split w into hi/lo bf16, packed in MFMA-fragment
// order (kills the 64-line B gather of round 4). (2) router_gemm: split-bf16
// MFMA, K-split x2, 64-row blocks, B staged via coalesced global_load_lds,
// f32 partials to d_ws. (3) router_epilogue: combine halves, softplus-noise,
// top-8 + sparse softmax, selective f64 near-tie repair (round-4-verified).

#define CDIM  2048
#define EDIM  64
#define NOUT  128
#define TOPK  8
#define NROWS 16384
#define BM    64
#define BK    32
#define KHALF 1024
#define NIT   (KHALF / BK)   // 32
#define TAU   1e-3f
#define XPS   72             // xsh row pitch (shorts): 36 dwords = 4 mod 32

typedef __attribute__((ext_vector_type(8))) short bf16x8;
typedef __attribute__((ext_vector_type(4))) float f32x4;

#define AS3(p) ((__attribute__((address_space(3))) void*)(p))
#define AS1(p) ((const __attribute__((address_space(1))) void*)(p))

__device__ __forceinline__ void split8(const float4 a, const float4 b,
                                       bf16x8& h8, bf16x8& l8) {
    const float vv[8] = {a.x, a.y, a.z, a.w, b.x, b.y, b.z, b.w};
    #pragma unroll
    for (int j = 0; j < 8; ++j) {
        const __bf16 h = (__bf16)vv[j];
        const __bf16 l = (__bf16)(vv[j] - (float)h);
        h8[j] = __builtin_bit_cast(short, h);
        l8[j] = __builtin_bit_cast(short, l);
    }
}

// ---- kernel 1: pack w into MFMA-fragment order, hi/lo bf16.
// slot s = (kc*8 + cg)*64 + lane holds w[col = cg*16 + (lane&15)]
//                                    [k = kc*32 + (lane>>4)*8 + j], j=0..7
__global__ __launch_bounds__(256)
void convert_w(const float* __restrict__ wr, const float* __restrict__ wn,
               short* __restrict__ whi, short* __restrict__ wlo) {
    const int s    = (int)blockIdx.x * 256 + (int)threadIdx.x;  // 0..32767
    const int lane = s & 63;
    const int cg   = (s >> 6) & 7;
    const int kc   = s >> 9;
    const int col  = cg * 16 + (lane & 15);
    const int k0   = kc * 32 + (lane >> 4) * 8;
    const float* src = (col < EDIM ? wr + (size_t)col * CDIM
                                   : wn + (size_t)(col - EDIM) * CDIM) + k0;
    const float4 a = *(const float4*)src;
    const float4 b = *(const float4*)(src + 4);
    bf16x8 h8, l8; split8(a, b, h8, l8);
    *(bf16x8*)(whi + (size_t)s * 8) = h8;
    *(bf16x8*)(wlo + (size_t)s * 8) = l8;
}

// ---- kernel 2: split-bf16 MFMA GEMM, K-split x2 -> f32 partials
__global__ __launch_bounds__(256, 2)
void router_gemm(const float* __restrict__ x,
                 const short* __restrict__ whi,
                 const short* __restrict__ wlo,
                 float* __restrict__ part)
{
    __shared__ __align__(16) short xsh[2][BM][XPS];     // hi[32]|lo[32]|pad
    __shared__ __align__(16) short bsh[2][2][8][512];   // [buf][h][cg][lane*8]

    const int tid  = (int)threadIdx.x;
    const int lane = tid & 63;
    const int wid  = tid >> 6;
    const int wr   = wid >> 1;          // row half of block tile (32 rows)
    const int wc   = wid & 1;           // col half (64 cols)
    const int l15  = lane & 15;
    const int q8   = (lane >> 4) * 8;
    const int q4   = (lane >> 4) * 4;
    const int half = (int)blockIdx.x & 1;
    const int row0 = ((int)blockIdx.x >> 1) * BM;

    // x staging role: thread covers row srow, k skk..skk+7
    const int srow = tid >> 2;          // 0..63
    const int skk  = (tid & 3) * 8;     // 0,8,16,24
    const float* xsrc = x + (size_t)(row0 + srow) * CDIM + half * KHALF + skk;

    f32x4 acc[2][4];
    #pragma unroll
    for (int mr = 0; mr < 2; ++mr)
        #pragma unroll
        for (int nc = 0; nc < 4; ++nc)
            acc[mr][nc] = (f32x4){0.f, 0.f, 0.f, 0.f};

    // B staging: wave stages col-groups 2*wid, 2*wid+1 (hi+lo), coalesced
    auto stageB = [&](int buf, int it) {
        const int kcg = half * NIT + it;
        #pragma unroll
        for (int c = 0; c < 2; ++c) {
            const int cg = wid * 2 + c;
            const size_t goff = (size_t)(kcg * 8 + cg) * 512 + lane * 8;
            __builtin_amdgcn_global_load_lds(AS1(whi + goff), AS3(&bsh[buf][0][cg][0]), 16, 0, 0);
            __builtin_amdgcn_global_load_lds(AS1(wlo + goff), AS3(&bsh[buf][1][cg][0]), 16, 0, 0);
        }
    };

    // prologue: stage chunk 0
    stageB(0, 0);
    {
        const float4 a = *(const float4*)xsrc;
        const float4 b = *(const float4*)(xsrc + 4);
        bf16x8 h8, l8; split8(a, b, h8, l8);
        *(bf16x8*)&xsh[0][srow][skk]      = h8;
        *(bf16x8*)&xsh[0][srow][32 + skk] = l8;
    }

    for (int it = 0; it < NIT; ++it) {
        const int cur = it & 1;
        __syncthreads();    // drains vmcnt (B stage) + lgkm (x writes) of prev
        const bool pf = (it + 1 < NIT);
        float4 pa, pb;
        if (pf) {
            stageB(cur ^ 1, it + 1);
            pa = *(const float4*)(xsrc + (it + 1) * BK);
            pb = *(const float4*)(xsrc + (it + 1) * BK + 4);
        }
        bf16x8 ah[2], al[2], bh[4], bl[4];
        #pragma unroll
        for (int mr = 0; mr < 2; ++mr) {
            const short* ar = &xsh[cur][wr * 32 + mr * 16 + l15][0];
            ah[mr] = *(const bf16x8*)(ar + q8);
            al[mr] = *(const bf16x8*)(ar + 32 + q8);
        }
        #pragma unroll
        for (int nc = 0; nc < 4; ++nc) {
            bh[nc] = *(const bf16x8*)&bsh[cur][0][wc * 4 + nc][lane * 8];
            bl[nc] = *(const bf16x8*)&bsh[cur][1][wc * 4 + nc][lane * 8];
        }
        #pragma unroll
        for (int mr = 0; mr < 2; ++mr)
            #pragma unroll
            for (int nc = 0; nc < 4; ++nc) {
                acc[mr][nc] = __builtin_amdgcn_mfma_f32_16x16x32_bf16(ah[mr], bh[nc], acc[mr][nc], 0, 0, 0);
                acc[mr][nc] = __builtin_amdgcn_mfma_f32_16x16x32_bf16(al[mr], bh[nc], acc[mr][nc], 0, 0, 0);
                acc[mr][nc] = __builtin_amdgcn_mfma_f32_16x16x32_bf16(ah[mr], bl[nc], acc[mr][nc], 0, 0, 0);
            }
        if (pf) {   // x loads have had the MFMA phase to land
            bf16x8 h8, l8; split8(pa, pb, h8, l8);
            *(bf16x8*)&xsh[cur ^ 1][srow][skk]      = h8;
            *(bf16x8*)&xsh[cur ^ 1][srow][32 + skk] = l8;
        }
    }

    // partial store (C/D layout: row = quad*4+reg, col = lane&15)
    float* dst = part + (size_t)half * NROWS * NOUT;
    #pragma unroll
    for (int mr = 0; mr < 2; ++mr)
        #pragma unroll
        for (int nc = 0; nc < 4; ++nc)
            #pragma unroll
            for (int g = 0; g < 4; ++g)
                dst[(size_t)(row0 + wr * 32 + mr * 16 + q4 + g) * NOUT
                    + wc * 64 + nc * 16 + l15] = acc[mr][nc][g];
}

// ---- kernel 3: combine halves + softplus-noise + top-8 + sparse softmax
__global__ __launch_bounds__(256)
void router_epilogue(const float* __restrict__ x,
                     const float* __restrict__ w_route,
                     const float* __restrict__ w_noise,
                     const float* __restrict__ noise,
                     const float* __restrict__ part,
                     float* __restrict__ out_probs,
                     float* __restrict__ out_idx)
{
    const int tid  = (int)threadIdx.x;
    const int lane = tid & 63;   // lane == expert index
    const int wid  = tid >> 6;
    const int row0 = (int)blockIdx.x * 64;
    const float* p0 = part;
    const float* p1 = part + (size_t)NROWS * NOUT;

    for (int rr = 0; rr < 16; ++rr) {
        const int grow = row0 + wid * 16 + rr;
        const size_t ro = (size_t)grow * NOUT;
        const float route = p0[ro + lane] + p1[ro + lane];
        const float nz    = p0[ro + EDIM + lane] + p1[ro + EDIM + lane];
        const float nv    = noise[(size_t)grow * EDIM + lane];
        const float sp = fmaxf(nz, 0.f) + log1pf(expf(-fabsf(nz)));
        const float nl = route + nv * sp;

        // top-8 + 9th, recording ambiguous boundaries (gap < TAU)
        float work = nl;
        int   rank = -1;
        float m = 0.f, prev = 0.f;
        bool amb = false, flagme = false;
        #pragma unroll
        for (int t = 0; t <= TOPK; ++t) {
            float bv = work;
            int   bi = lane;
            #pragma unroll
            for (int off = 32; off >= 1; off >>= 1) {
                const float ov = __shfl_xor(bv, off, 64);
                const int   oi = __shfl_xor(bi, off, 64);
                if (ov > bv || (ov == bv && oi < bi)) { bv = ov; bi = oi; }
            }
            if (t == 0) m = bv;
            else if (prev - bv < TAU) {
                amb = true;
                const float vb = 0.5f * (prev + bv);
                flagme = flagme || (fabsf(nl - vb) <= TAU);
            }
            prev = bv;
            if (lane == bi) { if (t < TOPK) rank = t; work = -INFINITY; }
        }

        if (!amb) {
            if (rank >= 0) out_idx[(size_t)grow * TOPK + rank] = (float)lane;
            float ev = (rank >= 0) ? expf(nl - m) : 0.f;
            float s  = ev;
            #pragma unroll
            for (int off = 32; off >= 1; off >>= 1) s += __shfl_xor(s, off, 64);
            out_probs[(size_t)grow * EDIM + lane] = ev / s;
        } else {
            // selective f64 repair: exact dots only for flagged experts
            unsigned long long mask = __ballot(flagme);
            double nld = (double)nl;
            const float* xr = x + (size_t)grow * CDIM;
            while (mask) {
                const int e = (int)__ffsll(mask) - 1;
                mask &= (mask - 1);
                double ar = 0.0, an = 0.0;
                const float* wrp = w_route + (size_t)e * CDIM;
                const float* wnp = w_noise + (size_t)e * CDIM;
                #pragma unroll
                for (int j = 0; j < 8; ++j) {
                    const int k = (j * 64 + lane) * 4;   // coalesced
                    const float4 xv = *(const float4*)(xr + k);
                    const float4 rv = *(const float4*)(wrp + k);
                    const float4 nq = *(const float4*)(wnp + k);
                    ar = fma((double)xv.x, (double)rv.x, ar);
                    ar = fma((double)xv.y, (double)rv.y, ar);
                    ar = fma((double)xv.z, (double)rv.z, ar);
                    ar = fma((double)xv.w, (double)rv.w, ar);
                    an = fma((double)xv.x, (double)nq.x, an);
                    an = fma((double)xv.y, (double)nq.y, an);
                    an = fma((double)xv.z, (double)nq.z, an);
                    an = fma((double)xv.w, (double)nq.w, an);
                }
                #pragma unroll
                for (int off = 32; off >= 1; off >>= 1) {
                    ar += __shfl_xor(ar, off, 64);
                    an += __shfl_xor(an, off, 64);
                }
                const double spd = fmax(an, 0.0) + log1p(exp(-fabs(an)));
                const double nve = (double)__shfl(nv, e, 64);
                const double v   = ar + nve * spd;
                if (lane == e) nld = v;
            }
            double workd = nld;
            int    rank2 = -1;
            double m2 = 0.0;
            #pragma unroll
            for (int t = 0; t < TOPK; ++t) {
                double bv = workd;
                int    bi = lane;
                #pragma unroll
                for (int off = 32; off >= 1; off >>= 1) {
                    const double ov = __shfl_xor(bv, off, 64);
                    const int    oi = __shfl_xor(bi, off, 64);
                    if (ov > bv || (ov == bv && oi < bi)) { bv = ov; bi = oi; }
                }
                if (t == 0) m2 = bv;
                if (lane == bi) {
                    rank2 = t;
                    workd = -INFINITY;
                    out_idx[(size_t)grow * TOPK + t] = (float)lane;
                }
            }
            float ev = (rank2 >= 0) ? expf((float)(nld - m2)) : 0.f;
            float s  = ev;
            #pragma unroll
            for (int off = 32; off >= 1; off >>= 1) s += __shfl_xor(s, off, 64);
            out_probs[(size_t)grow * EDIM + lane] = ev / s;
        }
    }
}

extern "C" void kernel_launch(void* const* d_in, const int* in_sizes, int n_in,
                              void* d_out, int out_size, void* d_ws, size_t ws_size,
                              hipStream_t stream)
{
    const float* x       = (const float*)d_in[0];
    const float* w_route = (const float*)d_in[1];
    const float* w_noise = (const float*)d_in[2];
    const float* noise   = (const float*)d_in[3];

    const int n_rows = in_sizes[0] / CDIM;                 // 16384
    float* out_probs = (float*)d_out;                      // (B,T,E) fp32
    float* out_idx   = out_probs + (size_t)n_rows * EDIM;  // (B,T,K) as fp32

    short* whi  = (short*)d_ws;                            // 512 KB packed hi
    short* wlo  = whi + (size_t)NOUT * CDIM;               // 512 KB packed lo
    float* part = (float*)((char*)d_ws + 2u * 1024u * 1024u); // 2 x 16384 x 128 f32

    hipLaunchKernelGGL(convert_w, dim3(NOUT * CDIM / (256 * 8)), dim3(256), 0, stream,
                       w_route, w_noise, whi, wlo);
    hipLaunchKernelGGL(router_gemm, dim3((n_rows / BM) * 2), dim3(256), 0, stream,
                       x, whi, wlo, part);
    hipLaunchKernelGGL(router_epilogue, dim3(n_rows / 64), dim3(256), 0, stream,
                       x, w_route, w_noise, noise, part, out_probs, out_idx);
}

// Round 6
// 254.845 us; speedup vs baseline: 2.5684x; 1.3589x over previous
//
#include <hip/hip_runtime.h>
#include <math.h>

// NoisyTopKRouter: B=4, T=4096, C=2048, E=64, K=8; rows = 16384.
// (1) convert_w: split w into hi/lo bf16 packed in MFMA-fragment order.
// (2) router_gemm: split-bf16 MFMA, K-split x2, x pre-split in LDS
//     (conflict-free pitch), B frags DIRECT from global (coalesced,
//     L2-resident, register double-buffered) -> f32 partials.
// (3) router_epilogue: rank-by-counting top-8 (no shfl chains), sparse
//     softmax, selective f64 near-tie repair (verified in rounds 4/5).

#define CDIM  2048
#define EDIM  64
#define NOUT  128
#define TOPK  8
#define NROWS 16384
#define BM    64
#define BK    32
#define KHALF 1024
#define NIT   (KHALF / BK)   // 32
#define TAU   1e-3f
#define XPS   72             // xsh pitch (shorts): 36 words -> 2-way reads (free)

typedef __attribute__((ext_vector_type(8))) short bf16x8;
typedef __attribute__((ext_vector_type(4))) float f32x4;

__device__ __forceinline__ void split8(const float4 a, const float4 b,
                                       bf16x8& h8, bf16x8& l8) {
    const float vv[8] = {a.x, a.y, a.z, a.w, b.x, b.y, b.z, b.w};
    #pragma unroll
    for (int j = 0; j < 8; ++j) {
        const __bf16 h = (__bf16)vv[j];
        const __bf16 l = (__bf16)(vv[j] - (float)h);
        h8[j] = __builtin_bit_cast(short, h);
        l8[j] = __builtin_bit_cast(short, l);
    }
}

// ---- kernel 1: pack w into MFMA-fragment order, hi/lo bf16.
// slot s = (kc*8 + cg)*64 + lane holds w[col = cg*16 + (lane&15)]
//                                    [k = kc*32 + (lane>>4)*8 + j]
__global__ __launch_bounds__(256)
void convert_w(const float* __restrict__ wr, const float* __restrict__ wn,
               short* __restrict__ whi, short* __restrict__ wlo) {
    const int s    = (int)blockIdx.x * 256 + (int)threadIdx.x;  // 0..32767
    const int lane = s & 63;
    const int cg   = (s >> 6) & 7;
    const int kc   = s >> 9;
    const int col  = cg * 16 + (lane & 15);
    const int k0   = kc * 32 + (lane >> 4) * 8;
    const float* src = (col < EDIM ? wr + (size_t)col * CDIM
                                   : wn + (size_t)(col - EDIM) * CDIM) + k0;
    const float4 a = *(const float4*)src;
    const float4 b = *(const float4*)(src + 4);
    bf16x8 h8, l8; split8(a, b, h8, l8);
    *(bf16x8*)(whi + (size_t)s * 8) = h8;
    *(bf16x8*)(wlo + (size_t)s * 8) = l8;
}

// ---- kernel 2: split-bf16 MFMA GEMM, K-split x2 -> f32 partials
__global__ __launch_bounds__(256, 2)
void router_gemm(const float* __restrict__ x,
                 const short* __restrict__ whi,
                 const short* __restrict__ wlo,
                 float* __restrict__ part)
{
    __shared__ __align__(16) short xsh[2][BM][XPS];   // hi[32]|lo[32]|pad

    const int tid  = (int)threadIdx.x;
    const int lane = tid & 63;
    const int wid  = tid >> 6;
    const int wr   = wid >> 1;          // row half (32 rows)
    const int wc   = wid & 1;           // col half (64 cols)
    const int l15  = lane & 15;
    const int q8   = (lane >> 4) * 8;
    const int q4   = (lane >> 4) * 4;
    const int half = (int)blockIdx.x & 1;
    const int row0 = ((int)blockIdx.x >> 1) * BM;

    const int srow = tid >> 2;          // 0..63
    const int skk  = (tid & 3) * 8;     // 0,8,16,24 (shorts)
    const float* xsrc = x + (size_t)(row0 + srow) * CDIM + half * KHALF + skk;

    f32x4 acc[2][4];
    #pragma unroll
    for (int mr = 0; mr < 2; ++mr)
        #pragma unroll
        for (int nc = 0; nc < 4; ++nc)
            acc[mr][nc] = (f32x4){0.f, 0.f, 0.f, 0.f};

    // B frags direct from global (packed, coalesced lane*16), dbl-buffered
    bf16x8 bh[2][4], bl[2][4];
    auto loadB = [&](int buf, int it) {
        const int base = ((half * NIT + it) * 8 + wc * 4) * 512 + lane * 8;
        #pragma unroll
        for (int nc = 0; nc < 4; ++nc) {
            bh[buf][nc] = *(const bf16x8*)(whi + base + nc * 512);
            bl[buf][nc] = *(const bf16x8*)(wlo + base + nc * 512);
        }
    };

    // prologue: B(0) + x-chunk(0)
    loadB(0, 0);
    {
        const float4 a = *(const float4*)xsrc;
        const float4 b = *(const float4*)(xsrc + 4);
        bf16x8 h8, l8; split8(a, b, h8, l8);
        *(bf16x8*)&xsh[0][srow][skk]      = h8;
        *(bf16x8*)&xsh[0][srow][32 + skk] = l8;
    }
    __syncthreads();

    #pragma unroll 2
    for (int it = 0; it < NIT; ++it) {
        const int  cur = it & 1;
        const bool pf  = (it + 1 < NIT);
        float4 pa, pb;
        if (pf) {   // issue next-iter loads early; consumed at end of this iter
            loadB(cur ^ 1, it + 1);
            pa = *(const float4*)(xsrc + (it + 1) * BK);
            pb = *(const float4*)(xsrc + (it + 1) * BK + 4);
        }
        bf16x8 ah[2], al[2];
        #pragma unroll
        for (int mr = 0; mr < 2; ++mr) {
            const short* ar = &xsh[cur][wr * 32 + mr * 16 + l15][0];
            ah[mr] = *(const bf16x8*)(ar + q8);
            al[mr] = *(const bf16x8*)(ar + 32 + q8);
        }
        #pragma unroll
        for (int mr = 0; mr < 2; ++mr)
            #pragma unroll
            for (int nc = 0; nc < 4; ++nc) {
                acc[mr][nc] = __builtin_amdgcn_mfma_f32_16x16x32_bf16(ah[mr], bh[cur][nc], acc[mr][nc], 0, 0, 0);
                acc[mr][nc] = __builtin_amdgcn_mfma_f32_16x16x32_bf16(al[mr], bh[cur][nc], acc[mr][nc], 0, 0, 0);
                acc[mr][nc] = __builtin_amdgcn_mfma_f32_16x16x32_bf16(ah[mr], bl[cur][nc], acc[mr][nc], 0, 0, 0);
            }
        if (pf) {   // x loads have had the whole MFMA phase to land
            bf16x8 h8, l8; split8(pa, pb, h8, l8);
            *(bf16x8*)&xsh[cur ^ 1][srow][skk]      = h8;
            *(bf16x8*)&xsh[cur ^ 1][srow][32 + skk] = l8;
        }
        __syncthreads();
    }

    // partial store (C/D layout: row = quad*4+reg, col = lane&15)
    float* dst = part + (size_t)half * NROWS * NOUT;
    #pragma unroll
    for (int mr = 0; mr < 2; ++mr)
        #pragma unroll
        for (int nc = 0; nc < 4; ++nc)
            #pragma unroll
            for (int g = 0; g < 4; ++g)
                dst[(size_t)(row0 + wr * 32 + mr * 16 + q4 + g) * NOUT
                    + wc * 64 + nc * 16 + l15] = acc[mr][nc][g];
}

// ---- kernel 3: rank-by-counting epilogue; wave = one row
__global__ __launch_bounds__(256)
void router_epilogue(const float* __restrict__ x,
                     const float* __restrict__ w_route,
                     const float* __restrict__ w_noise,
                     const float* __restrict__ noise,
                     const float* __restrict__ part,
                     float* __restrict__ out_probs,
                     float* __restrict__ out_idx)
{
    __shared__ float vals[4][64];
    __shared__ float srt[4][64];

    const int tid  = (int)threadIdx.x;
    const int lane = tid & 63;   // lane == expert index
    const int wid  = tid >> 6;
    const int grow = (int)blockIdx.x * 4 + wid;
    const float* p0 = part;
    const float* p1 = part + (size_t)NROWS * NOUT;

    const size_t ro = (size_t)grow * NOUT;
    const float route = p0[ro + lane] + p1[ro + lane];
    const float nz    = p0[ro + EDIM + lane] + p1[ro + EDIM + lane];
    const float nv    = noise[(size_t)grow * EDIM + lane];
    const float sp = fmaxf(nz, 0.f) + log1pf(expf(-fabsf(nz)));
    const float nl = route + nv * sp;

    vals[wid][lane] = nl;
    __syncthreads();

    // rank = #{j better than me}; "better" = (v_j > v_i) or tie with j < i
    int cnt = 0;
    #pragma unroll
    for (int jq = 0; jq < 16; ++jq) {
        const float4 v = *(const float4*)&vals[wid][jq * 4];
        const int j0 = jq * 4;
        cnt += (v.x > nl || (v.x == nl && (j0 + 0) < lane));
        cnt += (v.y > nl || (v.y == nl && (j0 + 1) < lane));
        cnt += (v.z > nl || (v.z == nl && (j0 + 2) < lane));
        cnt += (v.w > nl || (v.w == nl && (j0 + 3) < lane));
    }
    srt[wid][cnt] = nl;   // ranks are a permutation of 0..63
    __syncthreads();

    const float m = srt[wid][0];
    // gap scan over the 8 ranking-relevant boundaries (uniform per wave)
    bool amb = false, flagme = false;
    float prev = m;
    #pragma unroll
    for (int t = 1; t <= TOPK; ++t) {
        const float vt = srt[wid][t];
        if (prev - vt < TAU) {
            amb = true;
            const float vb = 0.5f * (prev + vt);
            flagme = flagme || (fabsf(nl - vb) <= TAU);
        }
        prev = vt;
    }

    if (cnt < TOPK) out_idx[(size_t)grow * TOPK + cnt] = (float)lane;
    float ev = (cnt < TOPK) ? expf(nl - m) : 0.f;
    float s  = ev;
    #pragma unroll
    for (int off = 32; off >= 1; off >>= 1) s += __shfl_xor(s, off, 64);
    out_probs[(size_t)grow * EDIM + lane] = ev / s;

    if (amb) {
        // selective f64 repair: exact dots only for flagged experts
        unsigned long long mask = __ballot(flagme);
        double nld = (double)nl;
        const float* xr = x + (size_t)grow * CDIM;
        while (mask) {
            const int e = (int)__ffsll(mask) - 1;
            mask &= (mask - 1);
            double ar = 0.0, an = 0.0;
            const float* wrp = w_route + (size_t)e * CDIM;
            const float* wnp = w_noise + (size_t)e * CDIM;
            #pragma unroll
            for (int j = 0; j < 8; ++j) {
                const int k = (j * 64 + lane) * 4;   // coalesced
                const float4 xv = *(const float4*)(xr + k);
                const float4 rv = *(const float4*)(wrp + k);
                const float4 nq = *(const float4*)(wnp + k);
                ar = fma((double)xv.x, (double)rv.x, ar);
                ar = fma((double)xv.y, (double)rv.y, ar);
                ar = fma((double)xv.z, (double)rv.z, ar);
                ar = fma((double)xv.w, (double)rv.w, ar);
                an = fma((double)xv.x, (double)nq.x, an);
                an = fma((double)xv.y, (double)nq.y, an);
                an = fma((double)xv.z, (double)nq.z, an);
                an = fma((double)xv.w, (double)nq.w, an);
            }
            #pragma unroll
            for (int off = 32; off >= 1; off >>= 1) {
                ar += __shfl_xor(ar, off, 64);
                an += __shfl_xor(an, off, 64);
            }
            const double spd = fmax(an, 0.0) + log1p(exp(-fabs(an)));
            const double nve = (double)__shfl(nv, e, 64);
            const double v   = ar + nve * spd;
            if (lane == e) nld = v;
        }
        double workd = nld;
        int    rank2 = -1;
        double m2 = 0.0;
        #pragma unroll
        for (int t = 0; t < TOPK; ++t) {
            double bv = workd;
            int    bi = lane;
            #pragma unroll
            for (int off = 32; off >= 1; off >>= 1) {
                const double ov = __shfl_xor(bv, off, 64);
                const int    oi = __shfl_xor(bi, off, 64);
                if (ov > bv || (ov == bv && oi < bi)) { bv = ov; bi = oi; }
            }
            if (t == 0) m2 = bv;
            if (lane == bi) {
                rank2 = t;
                workd = -INFINITY;
                out_idx[(size_t)grow * TOPK + t] = (float)lane;
            }
        }
        float ev2 = (rank2 >= 0) ? expf((float)(nld - m2)) : 0.f;
        float s2  = ev2;
        #pragma unroll
        for (int off = 32; off >= 1; off >>= 1) s2 += __shfl_xor(s2, off, 64);
        out_probs[(size_t)grow * EDIM + lane] = ev2 / s2;
    }
}

extern "C" void kernel_launch(void* const* d_in, const int* in_sizes, int n_in,
                              void* d_out, int out_size, void* d_ws, size_t ws_size,
                              hipStream_t stream)
{
    const float* x       = (const float*)d_in[0];
    const float* w_route = (const float*)d_in[1];
    const float* w_noise = (const float*)d_in[2];
    const float* noise   = (const float*)d_in[3];

    const int n_rows = in_sizes[0] / CDIM;                 // 16384
    float* out_probs = (float*)d_out;                      // (B,T,E) fp32
    float* out_idx   = out_probs + (size_t)n_rows * EDIM;  // (B,T,K) as fp32

    short* whi  = (short*)d_ws;                            // 512 KB packed hi
    short* wlo  = whi + (size_t)NOUT * CDIM;               // 512 KB packed lo
    float* part = (float*)((char*)d_ws + 2u * 1024u * 1024u); // 2 x 16384 x 128 f32

    hipLaunchKernelGGL(convert_w, dim3(NOUT * CDIM / (256 * 8)), dim3(256), 0, stream,
                       w_route, w_noise, whi, wlo);
    hipLaunchKernelGGL(router_gemm, dim3((n_rows / BM) * 2), dim3(256), 0, stream,
                       x, whi, wlo, part);
    hipLaunchKernelGGL(router_epilogue, dim3(n_rows / 4), dim3(256), 0, stream,
                       x, w_route, w_noise, noise, part, out_probs, out_idx);
}